// Round 4
// baseline (423.307 us; speedup 1.0000x reference)
//
#include <hip/hip_runtime.h>
#include <math.h>

#define N_NODES 10000
#define MPAD    10112   // 79 * 128
#define D_IN    1000
#define KPAD_IN 1024
#define D0      256
#define D1      128
#define NPAD_OUT 1024
#define NEG_SLOPE 0.2f

typedef __attribute__((ext_vector_type(8))) short short8;
typedef __attribute__((ext_vector_type(4))) float f32x4;

__device__ __forceinline__ ushort f2bf(float f) {
  union { float f; unsigned u; } c; c.f = f;
  unsigned r = c.u + 0x7FFF + ((c.u >> 16) & 1);   // RNE
  return (ushort)(r >> 16);
}
__device__ __forceinline__ float bf2f(ushort b) {
  union { unsigned u; float f; } c; c.u = ((unsigned)b) << 16;
  return c.f;
}

// ---------------- CSR build ----------------

__global__ void count_kernel(const int* __restrict__ idx, int E, int n, int* __restrict__ counts) {
  int k = blockIdx.x * blockDim.x + threadIdx.x;
  int tot = E + n;
  if (k >= tot) return;
  int dst = (k < E) ? idx[E + k] : (k - E);   // self-loops appended
  atomicAdd(&counts[dst], 1);
}

__global__ void scan_kernel(const int* __restrict__ counts, int* __restrict__ offsets,
                            int* __restrict__ cursors, int n) {
  __shared__ int tsum[1024];
  int tid = threadIdx.x;
  int per = (n + 1023) / 1024;
  int start = tid * per;
  int end = start + per; if (end > n) end = n;
  int s = 0;
  for (int i = start; i < end; i++) s += counts[i];
  tsum[tid] = s;
  __syncthreads();
  for (int off = 1; off < 1024; off <<= 1) {
    int v = (tid >= off) ? tsum[tid - off] : 0;
    __syncthreads();
    if (tid >= off) tsum[tid] += v;
    __syncthreads();
  }
  int run = (tid == 0) ? 0 : tsum[tid - 1];
  for (int i = start; i < end; i++) {
    offsets[i] = run; cursors[i] = run;
    run += counts[i];
  }
  if (tid == 1023) offsets[n] = tsum[1023];
}

__global__ void scatter_kernel(const int* __restrict__ idx, int E, int n,
                               int* __restrict__ cursors, int* __restrict__ srcs) {
  int k = blockIdx.x * blockDim.x + threadIdx.x;
  int tot = E + n;
  if (k >= tot) return;
  int src, dst;
  if (k < E) { src = idx[k]; dst = idx[E + k]; }
  else       { src = k - E;  dst = src; }
  int pos = atomicAdd(&cursors[dst], 1);
  srcs[pos] = src;
}

// ---------------- input / weight prep ----------------

// xb[r][k4*4..], r<MPAD: bf16(x) zero-padded; vectorized float4 -> ushort4
__global__ void conv_x_kernel(const float* __restrict__ x, ushort* __restrict__ xb) {
  int idx = blockIdx.x * blockDim.x + threadIdx.x;   // slot of 4 elems
  int r = idx >> 8, k4 = (idx & 255) * 4;
  ushort4 o = {0, 0, 0, 0};
  if (r < N_NODES && k4 < D_IN) {                    // D_IN divisible by 4
    float4 v = *(const float4*)(x + (size_t)r * D_IN + k4);
    o.x = f2bf(v.x); o.y = f2bf(v.y); o.z = f2bf(v.z); o.w = f2bf(v.w);
  }
  *(ushort4*)(xb + (size_t)idx * 4) = o;
}

// Wt[(n_off+n)*Kpad + k] = bf16(W[k*ldsrc + n]) with zero padding
__global__ void wprep_kernel(const float* __restrict__ W, ushort* __restrict__ Wt,
                             int K_src, int N_src, int ldsrc, int Kpad, int N_dst,
                             int n_off, int total) {
  int idx = blockIdx.x * blockDim.x + threadIdx.x;
  if (idx >= total) return;
  int n = idx / Kpad, k = idx - n * Kpad;
  float v = (k < K_src && n < N_src) ? W[(size_t)k * ldsrc + n] : 0.f;
  Wt[(size_t)(n_off + n) * Kpad + k] = f2bf(v);
}

__global__ void bprep_kernel(const float* __restrict__ bl1, const float* __restrict__ br1,
                             const float* __restrict__ bl2, const float* __restrict__ br2,
                             float* __restrict__ bcat1, float* __restrict__ bcat2) {
  int i = threadIdx.x;
  if (i < 128)      bcat1[i] = bl1[i];
  else if (i < 256) bcat1[i] = br1[i - 128];
  else if (i < 512) bcat2[i - 256] = bl2[i - 256];
  else              bcat2[i - 256] = br2[i - 512];
}

// ---------------- bf16 MFMA GEMM ----------------
// C[M,N] = A[M,K](bf16, lda) @ Bt[N,K](bf16, ldb)^T + bias
// 128x128 tile, BK=32, 4 waves (2x2), 16x16x32 MFMA, global_load_lds staging.
// MODE 0: f32 out guarded (ldp = ldc), MODE 1: bf16 out, pad rows zeroed (ldp = ldc),
// MODE 2: split — col<NL -> bf16 Cb[row*NL+col], col>=NL -> f32 Cf[row*NL+col-NL] (ldp = NL).

template<int MODE>
__launch_bounds__(256)
__global__ void gemm_mfma(const ushort* __restrict__ A, int lda,
                          const ushort* __restrict__ Bt, int ldb,
                          const float* __restrict__ bias,
                          float* __restrict__ Cf, ushort* __restrict__ Cb, int ldp,
                          int M_valid, int N_valid, int K) {
  constexpr int BK = 32;
  __shared__ ushort As[128 * BK];
  __shared__ ushort Bs[128 * BK];
  const int tid  = threadIdx.x;
  const int lane = tid & 63, wave = tid >> 6;
  const int wr = wave >> 1, wc = wave & 1;
  const int bm = blockIdx.y * 128, bn = blockIdx.x * 128;
  const int r16 = lane & 15, kb = lane >> 4;

  f32x4 acc[4][4] = {};

  const int srow = tid >> 2;
  const int scol = (tid & 3) * 8;    // ushort elems (16B)
  const ushort* Ag0 = A  + (size_t)(bm + srow) * lda + scol;
  const ushort* Ag1 = A  + (size_t)(bm + 64 + srow) * lda + scol;
  const ushort* Bg0 = Bt + (size_t)(bn + srow) * ldb + scol;
  const ushort* Bg1 = Bt + (size_t)(bn + 64 + srow) * ldb + scol;

  for (int k0 = 0; k0 < K; k0 += BK) {
    __builtin_amdgcn_global_load_lds((const __attribute__((address_space(1))) void*)(Ag0 + k0),
                                     (__attribute__((address_space(3))) void*)(As + tid * 8), 16, 0, 0);
    __builtin_amdgcn_global_load_lds((const __attribute__((address_space(1))) void*)(Ag1 + k0),
                                     (__attribute__((address_space(3))) void*)(As + 2048 + tid * 8), 16, 0, 0);
    __builtin_amdgcn_global_load_lds((const __attribute__((address_space(1))) void*)(Bg0 + k0),
                                     (__attribute__((address_space(3))) void*)(Bs + tid * 8), 16, 0, 0);
    __builtin_amdgcn_global_load_lds((const __attribute__((address_space(1))) void*)(Bg1 + k0),
                                     (__attribute__((address_space(3))) void*)(Bs + 2048 + tid * 8), 16, 0, 0);
    __syncthreads();

    short8 af[4], bfr[4];
    #pragma unroll
    for (int mi = 0; mi < 4; mi++)
      af[mi] = *(const short8*)(As + ((wr * 64 + mi * 16 + r16) * BK + kb * 8));
    #pragma unroll
    for (int ni = 0; ni < 4; ni++)
      bfr[ni] = *(const short8*)(Bs + ((wc * 64 + ni * 16 + r16) * BK + kb * 8));
    #pragma unroll
    for (int mi = 0; mi < 4; mi++)
      #pragma unroll
      for (int ni = 0; ni < 4; ni++)
        acc[mi][ni] = __builtin_amdgcn_mfma_f32_16x16x32_bf16(af[mi], bfr[ni], acc[mi][ni], 0, 0, 0);
    __syncthreads();
  }

  #pragma unroll
  for (int mi = 0; mi < 4; mi++) {
    const int row = bm + wr * 64 + mi * 16 + (lane >> 4) * 4;
    #pragma unroll
    for (int ni = 0; ni < 4; ni++) {
      const int col = bn + wc * 64 + ni * 16 + r16;
      const float bv = (col < N_valid) ? bias[col] : 0.f;
      #pragma unroll
      for (int r = 0; r < 4; r++) {
        const int gr = row + r;
        const float val = acc[mi][ni][r] + bv;
        if constexpr (MODE == 0) {
          if (gr < M_valid && col < N_valid) Cf[(size_t)gr * ldp + col] = val;
        } else if constexpr (MODE == 1) {
          Cb[(size_t)gr * ldp + col] = f2bf(gr < M_valid ? val : 0.f);
        } else {
          if (col < ldp) Cb[(size_t)gr * ldp + col] = f2bf(val);          // xl (bf16 gather table)
          else           Cf[(size_t)gr * ldp + (col - ldp)] = val;        // xr (f32)
        }
      }
    }
  }
}

// ---------------- fused GATv2 edge phase (per-dst-node block) ----------------
// xl gathered as bf16, stashed in LDS during logit pass, re-used for aggregation.

template<int D>
__launch_bounds__(D)
__global__ void gat_kernel(const ushort* __restrict__ xlb, const float* __restrict__ xrf,
                           const float* __restrict__ att, const float* __restrict__ bias,
                           const int* __restrict__ offsets, const int* __restrict__ srcs,
                           float* __restrict__ out_f32, ushort* __restrict__ out_bf16,
                           int n_valid) {
  constexpr int WAVES = D / 64;
  constexpr int EPL   = D / 64;   // dims per lane
  const int v    = blockIdx.x;
  const int tid  = threadIdx.x;
  const int lane = tid & 63;
  const int wave = tid >> 6;

  if (v >= n_valid) {               // pad rows -> zero bf16 row
    if (out_bf16) out_bf16[(size_t)v * D + tid] = 0;
    return;
  }

  __shared__ ushort xs[64][D];      // chunk's gathered bf16 rows
  __shared__ float xr_s[D];
  __shared__ float att_s[D];
  __shared__ float e_s[64];
  __shared__ float bc[3];           // [0]=scale, [1]=running max, [2]=running sum

  xr_s[tid]  = xrf[(size_t)v * D + tid];
  att_s[tid] = att[tid];
  if (tid == 0) { bc[1] = -INFINITY; bc[2] = 0.f; }
  const int beg = offsets[v], end = offsets[v + 1];
  float acc = 0.f;
  __syncthreads();

  for (int cbeg = beg; cbeg < end; cbeg += 64) {
    const int c = min(64, end - cbeg);

    // Phase A: per-edge logits, one wave per edge; stash bf16 row in LDS
    for (int k = wave; k < c; k += WAVES) {
      const int u = srcs[cbeg + k];
      float p = 0.f;
      if constexpr (EPL == 2) {
        const ushort2 xv = *(const ushort2*)(xlb + (size_t)u * D + lane * 2);
        *(ushort2*)(&xs[k][lane * 2]) = xv;
        const int d0 = lane * 2;
        float t0 = bf2f(xv.x) + xr_s[d0];     t0 = t0 > 0.f ? t0 : NEG_SLOPE * t0;
        float t1 = bf2f(xv.y) + xr_s[d0 + 1]; t1 = t1 > 0.f ? t1 : NEG_SLOPE * t1;
        p = t0 * att_s[d0] + t1 * att_s[d0 + 1];
      } else {
        const ushort4 xv = *(const ushort4*)(xlb + (size_t)u * D + lane * 4);
        *(ushort4*)(&xs[k][lane * 4]) = xv;
        const int d0 = lane * 4;
        float t0 = bf2f(xv.x) + xr_s[d0];     t0 = t0 > 0.f ? t0 : NEG_SLOPE * t0;
        float t1 = bf2f(xv.y) + xr_s[d0 + 1]; t1 = t1 > 0.f ? t1 : NEG_SLOPE * t1;
        float t2 = bf2f(xv.z) + xr_s[d0 + 2]; t2 = t2 > 0.f ? t2 : NEG_SLOPE * t2;
        float t3 = bf2f(xv.w) + xr_s[d0 + 3]; t3 = t3 > 0.f ? t3 : NEG_SLOPE * t3;
        p = t0 * att_s[d0] + t1 * att_s[d0 + 1] + t2 * att_s[d0 + 2] + t3 * att_s[d0 + 3];
      }
      #pragma unroll
      for (int off = 32; off > 0; off >>= 1) p += __shfl_xor(p, off);
      if (lane == 0) e_s[k] = p;
    }
    __syncthreads();

    // Phase B: chunk softmax merge (wave 0)
    if (wave == 0) {
      float e  = (lane < c) ? e_s[lane] : -INFINITY;
      float cm = e;
      #pragma unroll
      for (int off = 32; off > 0; off >>= 1) cm = fmaxf(cm, __shfl_xor(cm, off));
      const float m_old = bc[1];
      const float m_new = fmaxf(m_old, cm);
      float p = (lane < c) ? __expf(e - m_new) : 0.f;
      if (lane < c) e_s[lane] = p;
      #pragma unroll
      for (int off = 32; off > 0; off >>= 1) p += __shfl_xor(p, off);
      if (lane == 0) {
        const float scale = __expf(m_old - m_new);
        bc[0] = scale;
        bc[1] = m_new;
        bc[2] = bc[2] * scale + p;
      }
    }
    __syncthreads();

    // Phase C: rescale + aggregate from LDS stash
    acc *= bc[0];
    #pragma unroll 4
    for (int k = 0; k < c; k++) {
      acc = fmaf(e_s[k], bf2f(xs[k][tid]), acc);
    }
    __syncthreads();
  }

  const float val = acc / bc[2] + bias[tid];
  if (out_f32)  out_f32[(size_t)v * D + tid] = val;
  if (out_bf16) out_bf16[(size_t)v * D + tid] = f2bf(val);
}

// ---------------- launch ----------------

extern "C" void kernel_launch(void* const* d_in, const int* in_sizes, int n_in,
                              void* d_out, int out_size, void* d_ws, size_t ws_size,
                              hipStream_t stream) {
  const float* x     = (const float*)d_in[0];
  const int*   eidx  = (const int*)d_in[1];
  const float* Wpi   = (const float*)d_in[2];
  const float* bpi   = (const float*)d_in[3];
  const float* Wl1   = (const float*)d_in[4];
  const float* bl1   = (const float*)d_in[5];
  const float* Wr1   = (const float*)d_in[6];
  const float* br1   = (const float*)d_in[7];
  const float* att1  = (const float*)d_in[8];
  const float* bias1 = (const float*)d_in[9];
  const float* Wl2   = (const float*)d_in[10];
  const float* bl2   = (const float*)d_in[11];
  const float* Wr2   = (const float*)d_in[12];
  const float* br2   = (const float*)d_in[13];
  const float* att2  = (const float*)d_in[14];
  const float* bias2 = (const float*)d_in[15];
  const float* Wpo   = (const float*)d_in[16];
  const float* bpo   = (const float*)d_in[17];

  const int E    = in_sizes[1] / 2;
  const int n    = N_NODES;
  const int Etot = E + n;

  float* out_xhat = (float*)d_out;
  float* out_z    = (float*)d_out + (size_t)N_NODES * D_IN;

  // workspace carve-up
  char* wp = (char*)d_ws;
  auto alloc = [&](size_t bytes) { char* p = wp; wp += (bytes + 255) & ~(size_t)255; return p; };
  char* regionA = (char*)alloc((size_t)MPAD * KPAD_IN * 2);   // xb -> {xr1f,xl1b} -> {xr2f,xl2b}
  ushort* hb_db = (ushort*)alloc((size_t)MPAD * D0 * 2);      // hb then db
  ushort* zb    = (ushort*)alloc((size_t)MPAD * D1 * 2);
  int* counts  = (int*)alloc((size_t)n * 4);
  int* offsets = (int*)alloc((size_t)(n + 1) * 4);
  int* cursors = (int*)alloc((size_t)n * 4);
  int* srcs    = (int*)alloc((size_t)Etot * 4);
  ushort* Wpi_t = (ushort*)alloc((size_t)256 * 1024 * 2);
  ushort* W1cat = (ushort*)alloc((size_t)256 * 256 * 2);
  ushort* W2cat = (ushort*)alloc((size_t)512 * 128 * 2);
  ushort* Wpo_t = (ushort*)alloc((size_t)1024 * 256 * 2);
  float*  bcat1 = (float*)alloc(256 * 4);
  float*  bcat2 = (float*)alloc(512 * 4);

  ushort* xb   = (ushort*)regionA;
  // layer1 intermediates (alias regionA; xb dead by then)
  float*  xr1f = (float*)regionA;                                  // [MPAD][128] f32 (5.18 MB)
  ushort* xl1b = (ushort*)(regionA + 8 * 1024 * 1024);             // [MPAD][128] bf16 (2.59 MB)
  // layer2 intermediates (alias regionA; layer1 dead by then)
  float*  xr2f = (float*)regionA;                                  // [MPAD][256] f32 (10.35 MB)
  ushort* xl2b = (ushort*)(regionA + 12 * 1024 * 1024);            // [MPAD][256] bf16 (5.18 MB)
  ushort* hb   = hb_db;
  ushort* db   = hb_db;

  // CSR
  hipMemsetAsync(counts, 0, (size_t)n * 4, stream);
  const int tb = 256;
  count_kernel<<<(Etot + tb - 1) / tb, tb, 0, stream>>>(eidx, E, n, counts);
  scan_kernel<<<1, 1024, 0, stream>>>(counts, offsets, cursors, n);
  scatter_kernel<<<(Etot + tb - 1) / tb, tb, 0, stream>>>(eidx, E, n, cursors, srcs);

  // prep
  conv_x_kernel<<<MPAD, 256, 0, stream>>>(x, xb);
  wprep_kernel<<<(256 * 1024) / 256, 256, 0, stream>>>(Wpi, Wpi_t, 1000, 256, 256, 1024, 256, 0, 256 * 1024);
  wprep_kernel<<<(128 * 256) / 256, 256, 0, stream>>>(Wl1, W1cat, 256, 128, 128, 256, 128, 0, 128 * 256);
  wprep_kernel<<<(128 * 256) / 256, 256, 0, stream>>>(Wr1, W1cat, 256, 128, 128, 256, 128, 128, 128 * 256);
  wprep_kernel<<<(256 * 128) / 256, 256, 0, stream>>>(Wl2, W2cat, 128, 256, 256, 128, 256, 0, 256 * 128);
  wprep_kernel<<<(256 * 128) / 256, 256, 0, stream>>>(Wr2, W2cat, 128, 256, 256, 128, 256, 256, 256 * 128);
  wprep_kernel<<<(1024 * 256) / 256, 256, 0, stream>>>(Wpo, Wpo_t, 256, 1000, 1000, 256, 1024, 0, 1024 * 256);
  bprep_kernel<<<1, 768, 0, stream>>>(bl1, br1, bl2, br2, bcat1, bcat2);

  // h = x @ Wpi + bpi  (bf16 out, pad rows zeroed)
  gemm_mfma<1><<<dim3(D0 / 128, MPAD / 128), 256, 0, stream>>>(
      xb, KPAD_IN, Wpi_t, KPAD_IN, bpi, nullptr, hb, D0, N_NODES, D0, KPAD_IN);
  // [xl1(bf16)|xr1(f32)] = h @ [Wl1|Wr1] + [bl1|br1]  (split epilogue, NL=128)
  gemm_mfma<2><<<dim3(256 / 128, MPAD / 128), 256, 0, stream>>>(
      hb, D0, W1cat, D0, bcat1, xr1f, xl1b, D1, N_NODES, 256, D0);
  // z = GAT1 -> out_z (f32) + zb (bf16 padded)
  gat_kernel<D1><<<MPAD, D1, 0, stream>>>(xl1b, xr1f, att1, bias1,
                                          offsets, srcs, out_z, zb, N_NODES);
  // [xl2(bf16)|xr2(f32)] = z @ [Wl2|Wr2] + [bl2|br2]  (split epilogue, NL=256)
  gemm_mfma<2><<<dim3(512 / 128, MPAD / 128), 256, 0, stream>>>(
      zb, D1, W2cat, D1, bcat2, xr2f, xl2b, D0, N_NODES, 512, D1);
  // d = GAT2 -> db (bf16 padded)
  gat_kernel<D0><<<MPAD, D0, 0, stream>>>(xl2b, xr2f, att2, bias2,
                                          offsets, srcs, nullptr, db, N_NODES);
  // x_hat = d @ Wpo + bpo  (f32 out, guarded)
  gemm_mfma<0><<<dim3(NPAD_OUT / 128, MPAD / 128), 256, 0, stream>>>(
      db, D0, Wpo_t, D0, bpo, out_xhat, nullptr, D_IN, N_NODES, D_IN, D0);
}

// Round 5
// 387.015 us; speedup vs baseline: 1.0938x; 1.0938x over previous
//
#include <hip/hip_runtime.h>
#include <math.h>

#define N_NODES 10000
#define MPAD    10112   // 79 * 128
#define D_IN    1000
#define KPAD_IN 1024
#define D0      256
#define D1      128
#define NPAD_OUT 1024
#define NEG_SLOPE 0.2f

typedef __attribute__((ext_vector_type(8))) short short8;
typedef __attribute__((ext_vector_type(4))) float f32x4;

__device__ __forceinline__ ushort f2bf(float f) {
  union { float f; unsigned u; } c; c.f = f;
  unsigned r = c.u + 0x7FFF + ((c.u >> 16) & 1);   // RNE
  return (ushort)(r >> 16);
}
__device__ __forceinline__ float bf2f(ushort b) {
  union { unsigned u; float f; } c; c.u = ((unsigned)b) << 16;
  return c.f;
}

// ---------------- CSR build ----------------

__global__ void count_kernel(const int* __restrict__ idx, int E, int n, int* __restrict__ counts) {
  int k = blockIdx.x * blockDim.x + threadIdx.x;
  int tot = E + n;
  if (k >= tot) return;
  int dst = (k < E) ? idx[E + k] : (k - E);   // self-loops appended
  atomicAdd(&counts[dst], 1);
}

__global__ void scan_kernel(const int* __restrict__ counts, int* __restrict__ offsets,
                            int* __restrict__ cursors, int n) {
  __shared__ int tsum[1024];
  int tid = threadIdx.x;
  int per = (n + 1023) / 1024;
  int start = tid * per;
  int end = start + per; if (end > n) end = n;
  int s = 0;
  for (int i = start; i < end; i++) s += counts[i];
  tsum[tid] = s;
  __syncthreads();
  for (int off = 1; off < 1024; off <<= 1) {
    int v = (tid >= off) ? tsum[tid - off] : 0;
    __syncthreads();
    if (tid >= off) tsum[tid] += v;
    __syncthreads();
  }
  int run = (tid == 0) ? 0 : tsum[tid - 1];
  for (int i = start; i < end; i++) {
    offsets[i] = run; cursors[i] = run;
    run += counts[i];
  }
  if (tid == 1023) offsets[n] = tsum[1023];
}

__global__ void scatter_kernel(const int* __restrict__ idx, int E, int n,
                               int* __restrict__ cursors, int* __restrict__ srcs,
                               int* __restrict__ dsts) {
  int k = blockIdx.x * blockDim.x + threadIdx.x;
  int tot = E + n;
  if (k >= tot) return;
  int src, dst;
  if (k < E) { src = idx[k]; dst = idx[E + k]; }
  else       { src = k - E;  dst = src; }
  int pos = atomicAdd(&cursors[dst], 1);
  srcs[pos] = src;
  dsts[pos] = dst;
}

// ---------------- input / weight prep ----------------

__global__ void conv_x_kernel(const float* __restrict__ x, ushort* __restrict__ xb) {
  int idx = blockIdx.x * blockDim.x + threadIdx.x;   // slot of 4 elems
  int r = idx >> 8, k4 = (idx & 255) * 4;
  ushort4 o = {0, 0, 0, 0};
  if (r < N_NODES && k4 < D_IN) {                    // D_IN divisible by 4
    float4 v = *(const float4*)(x + (size_t)r * D_IN + k4);
    o.x = f2bf(v.x); o.y = f2bf(v.y); o.z = f2bf(v.z); o.w = f2bf(v.w);
  }
  *(ushort4*)(xb + (size_t)idx * 4) = o;
}

__global__ void wprep_kernel(const float* __restrict__ W, ushort* __restrict__ Wt,
                             int K_src, int N_src, int ldsrc, int Kpad, int N_dst,
                             int n_off, int total) {
  int idx = blockIdx.x * blockDim.x + threadIdx.x;
  if (idx >= total) return;
  int n = idx / Kpad, k = idx - n * Kpad;
  float v = (k < K_src && n < N_src) ? W[(size_t)k * ldsrc + n] : 0.f;
  Wt[(size_t)(n_off + n) * Kpad + k] = f2bf(v);
}

__global__ void bprep_kernel(const float* __restrict__ bl1, const float* __restrict__ br1,
                             const float* __restrict__ bl2, const float* __restrict__ br2,
                             float* __restrict__ bcat1, float* __restrict__ bcat2) {
  int i = threadIdx.x;
  if (i < 128)      bcat1[i] = bl1[i];
  else if (i < 256) bcat1[i] = br1[i - 128];
  else if (i < 512) bcat2[i - 256] = bl2[i - 256];
  else              bcat2[i - 256] = br2[i - 512];
}

// ---------------- bf16 MFMA GEMM ----------------
// C[M,N] = A[M,K](bf16, lda) @ Bt[N,K](bf16, ldb)^T + bias
// MODE 0: f32 out guarded, MODE 1: bf16 out (pad rows zeroed),
// MODE 2: split — col<ldp -> bf16 Cb, col>=ldp -> f32 Cf.

template<int MODE>
__launch_bounds__(256)
__global__ void gemm_mfma(const ushort* __restrict__ A, int lda,
                          const ushort* __restrict__ Bt, int ldb,
                          const float* __restrict__ bias,
                          float* __restrict__ Cf, ushort* __restrict__ Cb, int ldp,
                          int M_valid, int N_valid, int K) {
  constexpr int BK = 32;
  __shared__ ushort As[128 * BK];
  __shared__ ushort Bs[128 * BK];
  const int tid  = threadIdx.x;
  const int lane = tid & 63, wave = tid >> 6;
  const int wr = wave >> 1, wc = wave & 1;
  const int bm = blockIdx.y * 128, bn = blockIdx.x * 128;
  const int r16 = lane & 15, kb = lane >> 4;

  f32x4 acc[4][4] = {};

  const int srow = tid >> 2;
  const int scol = (tid & 3) * 8;    // ushort elems (16B)
  const ushort* Ag0 = A  + (size_t)(bm + srow) * lda + scol;
  const ushort* Ag1 = A  + (size_t)(bm + 64 + srow) * lda + scol;
  const ushort* Bg0 = Bt + (size_t)(bn + srow) * ldb + scol;
  const ushort* Bg1 = Bt + (size_t)(bn + 64 + srow) * ldb + scol;

  for (int k0 = 0; k0 < K; k0 += BK) {
    __builtin_amdgcn_global_load_lds((const __attribute__((address_space(1))) void*)(Ag0 + k0),
                                     (__attribute__((address_space(3))) void*)(As + tid * 8), 16, 0, 0);
    __builtin_amdgcn_global_load_lds((const __attribute__((address_space(1))) void*)(Ag1 + k0),
                                     (__attribute__((address_space(3))) void*)(As + 2048 + tid * 8), 16, 0, 0);
    __builtin_amdgcn_global_load_lds((const __attribute__((address_space(1))) void*)(Bg0 + k0),
                                     (__attribute__((address_space(3))) void*)(Bs + tid * 8), 16, 0, 0);
    __builtin_amdgcn_global_load_lds((const __attribute__((address_space(1))) void*)(Bg1 + k0),
                                     (__attribute__((address_space(3))) void*)(Bs + 2048 + tid * 8), 16, 0, 0);
    __syncthreads();

    short8 af[4], bfr[4];
    #pragma unroll
    for (int mi = 0; mi < 4; mi++)
      af[mi] = *(const short8*)(As + ((wr * 64 + mi * 16 + r16) * BK + kb * 8));
    #pragma unroll
    for (int ni = 0; ni < 4; ni++)
      bfr[ni] = *(const short8*)(Bs + ((wc * 64 + ni * 16 + r16) * BK + kb * 8));
    #pragma unroll
    for (int mi = 0; mi < 4; mi++)
      #pragma unroll
      for (int ni = 0; ni < 4; ni++)
        acc[mi][ni] = __builtin_amdgcn_mfma_f32_16x16x32_bf16(af[mi], bfr[ni], acc[mi][ni], 0, 0, 0);
    __syncthreads();
  }

  #pragma unroll
  for (int mi = 0; mi < 4; mi++) {
    const int row = bm + wr * 64 + mi * 16 + (lane >> 4) * 4;
    #pragma unroll
    for (int ni = 0; ni < 4; ni++) {
      const int col = bn + wc * 64 + ni * 16 + r16;
      const float bv = (col < N_valid) ? bias[col] : 0.f;
      #pragma unroll
      for (int r = 0; r < 4; r++) {
        const int gr = row + r;
        const float val = acc[mi][ni][r] + bv;
        if constexpr (MODE == 0) {
          if (gr < M_valid && col < N_valid) Cf[(size_t)gr * ldp + col] = val;
        } else if constexpr (MODE == 1) {
          Cb[(size_t)gr * ldp + col] = f2bf(gr < M_valid ? val : 0.f);
        } else {
          if (col < ldp) Cb[(size_t)gr * ldp + col] = f2bf(val);          // xl (bf16 gather table)
          else           Cf[(size_t)gr * ldp + (col - ldp)] = val;        // xr (f32)
        }
      }
    }
  }
}

// ---------------- GATv2 edge phase, stage 1: edge-parallel logits ----------------
// e[k] = dot(leakyrelu(xl[src[k]] + xr[dst[k]]), att); one LPE-lane group per edge.

template<int D>
__launch_bounds__(256)
__global__ void glogit_kernel(const ushort* __restrict__ xlb, const float* __restrict__ xrf,
                              const float* __restrict__ att,
                              const int* __restrict__ srcs, const int* __restrict__ dsts,
                              float* __restrict__ e, int Etot) {
  constexpr int LPE = D / 4;         // lanes per edge (64 for D=256, 32 for D=128)
  const int tid = threadIdx.x;
  const int sub = tid & (LPE - 1);
  const int d0  = sub * 4;
  __shared__ float att_s[D];
  if (tid < D) att_s[tid] = att[tid];
  __syncthreads();
  const int grp  = (blockIdx.x * 256 + tid) / LPE;
  const int ngrp = (gridDim.x * 256) / LPE;
  for (int k = grp; k < Etot; k += ngrp) {
    const int u = srcs[k], v = dsts[k];
    const ushort4 xv = *(const ushort4*)(xlb + (size_t)u * D + d0);
    const float4  rv = *(const float4*)(xrf + (size_t)v * D + d0);
    float t0 = bf2f(xv.x) + rv.x; t0 = t0 > 0.f ? t0 : NEG_SLOPE * t0;
    float t1 = bf2f(xv.y) + rv.y; t1 = t1 > 0.f ? t1 : NEG_SLOPE * t1;
    float t2 = bf2f(xv.z) + rv.z; t2 = t2 > 0.f ? t2 : NEG_SLOPE * t2;
    float t3 = bf2f(xv.w) + rv.w; t3 = t3 > 0.f ? t3 : NEG_SLOPE * t3;
    float p = t0 * att_s[d0] + t1 * att_s[d0 + 1] + t2 * att_s[d0 + 2] + t3 * att_s[d0 + 3];
    #pragma unroll
    for (int off = LPE / 2; off > 0; off >>= 1) p += __shfl_xor(p, off);
    if (sub == 0) e[k] = p;
  }
}

// ---------------- GATv2 edge phase, stage 2: per-dst softmax + aggregate ----------------

template<int D>
__launch_bounds__(D)
__global__ void gagg_kernel(const ushort* __restrict__ xlb, const float* __restrict__ e,
                            const float* __restrict__ bias,
                            const int* __restrict__ offsets, const int* __restrict__ srcs,
                            float* __restrict__ out_f32, ushort* __restrict__ out_bf16,
                            int n_valid) {
  constexpr int WAVES = D / 64;
  constexpr int CH = 512;
  const int v    = blockIdx.x;
  const int tid  = threadIdx.x;
  const int lane = tid & 63;
  const int wave = tid >> 6;

  if (v >= n_valid) {               // pad rows -> zero bf16 row
    if (out_bf16) out_bf16[(size_t)v * D + tid] = 0;
    return;
  }

  __shared__ float al_s[CH];
  __shared__ int   us_s[CH];
  __shared__ float red[WAVES];
  __shared__ float bc[2];           // [0]=running max, [1]=running sum

  const int beg = offsets[v], end = offsets[v + 1];
  if (tid == 0) { bc[0] = -INFINITY; bc[1] = 0.f; }
  float acc = 0.f;
  __syncthreads();

  for (int cbeg = beg; cbeg < end; cbeg += CH) {
    const int c = min(CH, end - cbeg);

    // cooperative load + partial max
    float pmax = -INFINITY;
    for (int k = tid; k < c; k += D) {
      const float ev = e[cbeg + k];
      al_s[k] = ev;
      us_s[k] = srcs[cbeg + k];
      pmax = fmaxf(pmax, ev);
    }
    #pragma unroll
    for (int off = 32; off > 0; off >>= 1) pmax = fmaxf(pmax, __shfl_xor(pmax, off));
    if (lane == 0) red[wave] = pmax;
    __syncthreads();

    float m = red[0];
    #pragma unroll
    for (int w = 1; w < WAVES; w++) m = fmaxf(m, red[w]);
    const float m_old = bc[0];
    const float m_new = fmaxf(m_old, m);
    const float scale = __expf(m_old - m_new);     // first chunk: exp(-inf)=0
    __syncthreads();                               // done reading red/bc

    // exp + partial sum
    float psum = 0.f;
    for (int k = tid; k < c; k += D) {
      const float p = __expf(al_s[k] - m_new);
      al_s[k] = p;
      psum += p;
    }
    #pragma unroll
    for (int off = 32; off > 0; off >>= 1) psum += __shfl_xor(psum, off);
    if (lane == 0) red[wave] = psum;
    __syncthreads();

    if (tid == 0) {
      float s = 0.f;
      #pragma unroll
      for (int w = 0; w < WAVES; w++) s += red[w];
      bc[0] = m_new;
      bc[1] = bc[1] * scale + s;
    }

    // aggregate: 4 independent accumulators to pipeline the gather stream
    float a0 = 0.f, a1 = 0.f, a2 = 0.f, a3 = 0.f;
    int k = 0;
    for (; k + 4 <= c; k += 4) {
      a0 = fmaf(al_s[k],     bf2f(xlb[(size_t)us_s[k]     * D + tid]), a0);
      a1 = fmaf(al_s[k + 1], bf2f(xlb[(size_t)us_s[k + 1] * D + tid]), a1);
      a2 = fmaf(al_s[k + 2], bf2f(xlb[(size_t)us_s[k + 2] * D + tid]), a2);
      a3 = fmaf(al_s[k + 3], bf2f(xlb[(size_t)us_s[k + 3] * D + tid]), a3);
    }
    for (; k < c; k++)
      a0 = fmaf(al_s[k], bf2f(xlb[(size_t)us_s[k] * D + tid]), a0);
    acc = acc * scale + (a0 + a1) + (a2 + a3);
    __syncthreads();   // protect al_s/us_s for next chunk
  }

  const float val = acc / bc[1] + bias[tid];
  if (out_f32)  out_f32[(size_t)v * D + tid] = val;
  if (out_bf16) out_bf16[(size_t)v * D + tid] = f2bf(val);
}

// ---------------- launch ----------------

extern "C" void kernel_launch(void* const* d_in, const int* in_sizes, int n_in,
                              void* d_out, int out_size, void* d_ws, size_t ws_size,
                              hipStream_t stream) {
  const float* x     = (const float*)d_in[0];
  const int*   eidx  = (const int*)d_in[1];
  const float* Wpi   = (const float*)d_in[2];
  const float* bpi   = (const float*)d_in[3];
  const float* Wl1   = (const float*)d_in[4];
  const float* bl1   = (const float*)d_in[5];
  const float* Wr1   = (const float*)d_in[6];
  const float* br1   = (const float*)d_in[7];
  const float* att1  = (const float*)d_in[8];
  const float* bias1 = (const float*)d_in[9];
  const float* Wl2   = (const float*)d_in[10];
  const float* bl2   = (const float*)d_in[11];
  const float* Wr2   = (const float*)d_in[12];
  const float* br2   = (const float*)d_in[13];
  const float* att2  = (const float*)d_in[14];
  const float* bias2 = (const float*)d_in[15];
  const float* Wpo   = (const float*)d_in[16];
  const float* bpo   = (const float*)d_in[17];

  const int E    = in_sizes[1] / 2;
  const int n    = N_NODES;
  const int Etot = E + n;

  float* out_xhat = (float*)d_out;
  float* out_z    = (float*)d_out + (size_t)N_NODES * D_IN;

  // workspace carve-up
  char* wp = (char*)d_ws;
  auto alloc = [&](size_t bytes) { char* p = wp; wp += (bytes + 255) & ~(size_t)255; return p; };
  char* regionA = (char*)alloc((size_t)MPAD * KPAD_IN * 2);   // xb -> {xr1f,xl1b} -> {xr2f,xl2b}
  ushort* hb_db = (ushort*)alloc((size_t)MPAD * D0 * 2);      // hb then db
  ushort* zb    = (ushort*)alloc((size_t)MPAD * D1 * 2);
  int* counts  = (int*)alloc((size_t)n * 4);
  int* offsets = (int*)alloc((size_t)(n + 1) * 4);
  int* cursors = (int*)alloc((size_t)n * 4);
  int* srcs    = (int*)alloc((size_t)Etot * 4);
  int* dsts    = (int*)alloc((size_t)Etot * 4);
  float* evals = (float*)alloc((size_t)Etot * 4);
  ushort* Wpi_t = (ushort*)alloc((size_t)256 * 1024 * 2);
  ushort* W1cat = (ushort*)alloc((size_t)256 * 256 * 2);
  ushort* W2cat = (ushort*)alloc((size_t)512 * 128 * 2);
  ushort* Wpo_t = (ushort*)alloc((size_t)1024 * 256 * 2);
  float*  bcat1 = (float*)alloc(256 * 4);
  float*  bcat2 = (float*)alloc(512 * 4);

  ushort* xb   = (ushort*)regionA;
  // layer1 intermediates (alias regionA; xb dead by then)
  float*  xr1f = (float*)regionA;                                  // [MPAD][128] f32
  ushort* xl1b = (ushort*)(regionA + 8 * 1024 * 1024);             // [MPAD][128] bf16
  // layer2 intermediates (alias regionA; layer1 dead by then)
  float*  xr2f = (float*)regionA;                                  // [MPAD][256] f32
  ushort* xl2b = (ushort*)(regionA + 12 * 1024 * 1024);            // [MPAD][256] bf16
  ushort* hb   = hb_db;
  ushort* db   = hb_db;

  // CSR
  hipMemsetAsync(counts, 0, (size_t)n * 4, stream);
  const int tb = 256;
  count_kernel<<<(Etot + tb - 1) / tb, tb, 0, stream>>>(eidx, E, n, counts);
  scan_kernel<<<1, 1024, 0, stream>>>(counts, offsets, cursors, n);
  scatter_kernel<<<(Etot + tb - 1) / tb, tb, 0, stream>>>(eidx, E, n, cursors, srcs, dsts);

  // prep
  conv_x_kernel<<<MPAD, 256, 0, stream>>>(x, xb);
  wprep_kernel<<<(256 * 1024) / 256, 256, 0, stream>>>(Wpi, Wpi_t, 1000, 256, 256, 1024, 256, 0, 256 * 1024);
  wprep_kernel<<<(128 * 256) / 256, 256, 0, stream>>>(Wl1, W1cat, 256, 128, 128, 256, 128, 0, 128 * 256);
  wprep_kernel<<<(128 * 256) / 256, 256, 0, stream>>>(Wr1, W1cat, 256, 128, 128, 256, 128, 128, 128 * 256);
  wprep_kernel<<<(256 * 128) / 256, 256, 0, stream>>>(Wl2, W2cat, 128, 256, 256, 128, 256, 0, 256 * 128);
  wprep_kernel<<<(256 * 128) / 256, 256, 0, stream>>>(Wr2, W2cat, 128, 256, 256, 128, 256, 256, 256 * 128);
  wprep_kernel<<<(1024 * 256) / 256, 256, 0, stream>>>(Wpo, Wpo_t, 256, 1000, 1000, 256, 1024, 0, 1024 * 256);
  bprep_kernel<<<1, 768, 0, stream>>>(bl1, br1, bl2, br2, bcat1, bcat2);

  // h = x @ Wpi + bpi  (bf16 out, pad rows zeroed)
  gemm_mfma<1><<<dim3(D0 / 128, MPAD / 128), 256, 0, stream>>>(
      xb, KPAD_IN, Wpi_t, KPAD_IN, bpi, nullptr, hb, D0, N_NODES, D0, KPAD_IN);
  // [xl1(bf16)|xr1(f32)] = h @ [Wl1|Wr1] + [bl1|br1]  (split epilogue, NL=128)
  gemm_mfma<2><<<dim3(256 / 128, MPAD / 128), 256, 0, stream>>>(
      hb, D0, W1cat, D0, bcat1, xr1f, xl1b, D1, N_NODES, 256, D0);
  // GAT1: logits then softmax+aggregate -> out_z (f32) + zb (bf16 padded)
  glogit_kernel<D1><<<2048, 256, 0, stream>>>(xl1b, xr1f, att1, srcs, dsts, evals, Etot);
  gagg_kernel<D1><<<MPAD, D1, 0, stream>>>(xl1b, evals, bias1, offsets, srcs, out_z, zb, N_NODES);
  // [xl2(bf16)|xr2(f32)] = z @ [Wl2|Wr2] + [bl2|br2]  (split epilogue, NL=256)
  gemm_mfma<2><<<dim3(512 / 128, MPAD / 128), 256, 0, stream>>>(
      zb, D1, W2cat, D1, bcat2, xr2f, xl2b, D0, N_NODES, 512, D1);
  // GAT2
  glogit_kernel<D0><<<2048, 256, 0, stream>>>(xl2b, xr2f, att2, srcs, dsts, evals, Etot);
  gagg_kernel<D0><<<MPAD, D0, 0, stream>>>(xl2b, evals, bias2, offsets, srcs, nullptr, db, N_NODES);
  // x_hat = d @ Wpo + bpo  (f32 out, guarded)
  gemm_mfma<0><<<dim3(NPAD_OUT / 128, MPAD / 128), 256, 0, stream>>>(
      db, D0, Wpo_t, D0, bpo, out_xhat, nullptr, D_IN, N_NODES, D_IN, D0);
}

// Round 6
// 345.957 us; speedup vs baseline: 1.2236x; 1.1187x over previous
//
#include <hip/hip_runtime.h>
#include <math.h>

#define N_NODES 10000
#define MPAD    10112   // 79 * 128
#define D_IN    1000
#define KPAD_IN 1024
#define D0      256
#define D1      128
#define NPAD_OUT 1024
#define NEG_SLOPE 0.2f

typedef __attribute__((ext_vector_type(8))) short short8;
typedef __attribute__((ext_vector_type(4))) float f32x4;

__device__ __forceinline__ ushort f2bf(float f) {
  union { float f; unsigned u; } c; c.f = f;
  unsigned r = c.u + 0x7FFF + ((c.u >> 16) & 1);   // RNE
  return (ushort)(r >> 16);
}
__device__ __forceinline__ float bf2f(ushort b) {
  union { unsigned u; float f; } c; c.u = ((unsigned)b) << 16;
  return c.f;
}

// ---------------- CSR build ----------------

__global__ void count_kernel(const int* __restrict__ idx, int E, int n, int* __restrict__ counts) {
  int k = blockIdx.x * blockDim.x + threadIdx.x;
  int tot = E + n;
  if (k >= tot) return;
  int dst = (k < E) ? idx[E + k] : (k - E);   // self-loops appended
  atomicAdd(&counts[dst], 1);
}

__global__ void scan_kernel(const int* __restrict__ counts, int* __restrict__ offsets,
                            int* __restrict__ cursors, int n) {
  __shared__ int tsum[1024];
  int tid = threadIdx.x;
  int per = (n + 1023) / 1024;
  int start = tid * per;
  int end = start + per; if (end > n) end = n;
  int s = 0;
  for (int i = start; i < end; i++) s += counts[i];
  tsum[tid] = s;
  __syncthreads();
  for (int off = 1; off < 1024; off <<= 1) {
    int v = (tid >= off) ? tsum[tid - off] : 0;
    __syncthreads();
    if (tid >= off) tsum[tid] += v;
    __syncthreads();
  }
  int run = (tid == 0) ? 0 : tsum[tid - 1];
  for (int i = start; i < end; i++) {
    offsets[i] = run; cursors[i] = run;
    run += counts[i];
  }
  if (tid == 1023) offsets[n] = tsum[1023];
}

__global__ void scatter_kernel(const int* __restrict__ idx, int E, int n,
                               int* __restrict__ cursors, int* __restrict__ srcs) {
  int k = blockIdx.x * blockDim.x + threadIdx.x;
  int tot = E + n;
  if (k >= tot) return;
  int src, dst;
  if (k < E) { src = idx[k]; dst = idx[E + k]; }
  else       { src = k - E;  dst = src; }
  int pos = atomicAdd(&cursors[dst], 1);
  srcs[pos] = src;
}

// ---------------- input / weight prep ----------------

__global__ void conv_x_kernel(const float* __restrict__ x, ushort* __restrict__ xb) {
  int idx = blockIdx.x * blockDim.x + threadIdx.x;   // slot of 4 elems
  int r = idx >> 8, k4 = (idx & 255) * 4;
  ushort4 o = {0, 0, 0, 0};
  if (r < N_NODES && k4 < D_IN) {                    // D_IN divisible by 4
    float4 v = *(const float4*)(x + (size_t)r * D_IN + k4);
    o.x = f2bf(v.x); o.y = f2bf(v.y); o.z = f2bf(v.z); o.w = f2bf(v.w);
  }
  *(ushort4*)(xb + (size_t)idx * 4) = o;
}

// all weight transposes + bias concats in one launch
#define T_WPI   (256 * 1024)
#define T_W1    (256 * 256)
#define T_W2    (512 * 128)
#define T_WPO   (1024 * 256)
#define OFF_W1  T_WPI
#define OFF_W2  (OFF_W1 + T_W1)
#define OFF_WPO (OFF_W2 + T_W2)
#define OFF_B   (OFF_WPO + T_WPO)
#define T_ALL   (OFF_B + 768)

__global__ void wprep_all(const float* __restrict__ Wpi,
                          const float* __restrict__ Wl1, const float* __restrict__ Wr1,
                          const float* __restrict__ Wl2, const float* __restrict__ Wr2,
                          const float* __restrict__ Wpo,
                          const float* __restrict__ bl1, const float* __restrict__ br1,
                          const float* __restrict__ bl2, const float* __restrict__ br2,
                          ushort* __restrict__ Wpi_t, ushort* __restrict__ W1cat,
                          ushort* __restrict__ W2cat, ushort* __restrict__ Wpo_t,
                          float* __restrict__ bcat1, float* __restrict__ bcat2) {
  int idx = blockIdx.x * 256 + threadIdx.x;
  if (idx >= T_ALL) return;
  if (idx < OFF_W1) {                       // Wpi_t [256][1024] <- Wpi [1000][256]
    int n = idx >> 10, k = idx & 1023;
    Wpi_t[idx] = f2bf((k < 1000) ? Wpi[(size_t)k * 256 + n] : 0.f);
  } else if (idx < OFF_W2) {                // W1cat [256][256] <- Wl1|Wr1 [256][128]
    int q = idx - OFF_W1, n = q >> 8, k = q & 255;
    float v = (n < 128) ? Wl1[k * 128 + n] : Wr1[k * 128 + (n - 128)];
    W1cat[q] = f2bf(v);
  } else if (idx < OFF_WPO) {               // W2cat [512][128] <- Wl2|Wr2 [128][256]
    int q = idx - OFF_W2, n = q >> 7, k = q & 127;
    float v = (n < 256) ? Wl2[k * 256 + n] : Wr2[k * 256 + (n - 256)];
    W2cat[q] = f2bf(v);
  } else if (idx < OFF_B) {                 // Wpo_t [1024][256] <- Wpo [256][1000]
    int q = idx - OFF_WPO, n = q >> 8, k = q & 255;
    Wpo_t[q] = f2bf((n < 1000) ? Wpo[(size_t)k * 1000 + n] : 0.f);
  } else {
    int q = idx - OFF_B;
    if (q < 128)      bcat1[q] = bl1[q];
    else if (q < 256) bcat1[q] = br1[q - 128];
    else if (q < 512) bcat2[q - 256] = bl2[q - 256];
    else              bcat2[q - 256] = br2[q - 512];
  }
}

// ---------------- bf16 MFMA GEMM ----------------
// C[M,N] = A[M,K](bf16, lda) @ Bt[N,K](bf16, ldb)^T + bias
// MODE 0: f32 out guarded, MODE 1: bf16 out (pad rows zeroed),
// MODE 2: split — col<ldp -> bf16 Cb, col>=ldp -> f32 Cf.

template<int MODE>
__launch_bounds__(256)
__global__ void gemm_mfma(const ushort* __restrict__ A, int lda,
                          const ushort* __restrict__ Bt, int ldb,
                          const float* __restrict__ bias,
                          float* __restrict__ Cf, ushort* __restrict__ Cb, int ldp,
                          int M_valid, int N_valid, int K) {
  constexpr int BK = 32;
  __shared__ ushort As[128 * BK];
  __shared__ ushort Bs[128 * BK];
  const int tid  = threadIdx.x;
  const int lane = tid & 63, wave = tid >> 6;
  const int wr = wave >> 1, wc = wave & 1;
  const int bm = blockIdx.y * 128, bn = blockIdx.x * 128;
  const int r16 = lane & 15, kb = lane >> 4;

  f32x4 acc[4][4] = {};

  const int srow = tid >> 2;
  const int scol = (tid & 3) * 8;    // ushort elems (16B)
  const ushort* Ag0 = A  + (size_t)(bm + srow) * lda + scol;
  const ushort* Ag1 = A  + (size_t)(bm + 64 + srow) * lda + scol;
  const ushort* Bg0 = Bt + (size_t)(bn + srow) * ldb + scol;
  const ushort* Bg1 = Bt + (size_t)(bn + 64 + srow) * ldb + scol;

  for (int k0 = 0; k0 < K; k0 += BK) {
    __builtin_amdgcn_global_load_lds((const __attribute__((address_space(1))) void*)(Ag0 + k0),
                                     (__attribute__((address_space(3))) void*)(As + tid * 8), 16, 0, 0);
    __builtin_amdgcn_global_load_lds((const __attribute__((address_space(1))) void*)(Ag1 + k0),
                                     (__attribute__((address_space(3))) void*)(As + 2048 + tid * 8), 16, 0, 0);
    __builtin_amdgcn_global_load_lds((const __attribute__((address_space(1))) void*)(Bg0 + k0),
                                     (__attribute__((address_space(3))) void*)(Bs + tid * 8), 16, 0, 0);
    __builtin_amdgcn_global_load_lds((const __attribute__((address_space(1))) void*)(Bg1 + k0),
                                     (__attribute__((address_space(3))) void*)(Bs + 2048 + tid * 8), 16, 0, 0);
    __syncthreads();

    short8 af[4], bfr[4];
    #pragma unroll
    for (int mi = 0; mi < 4; mi++)
      af[mi] = *(const short8*)(As + ((wr * 64 + mi * 16 + r16) * BK + kb * 8));
    #pragma unroll
    for (int ni = 0; ni < 4; ni++)
      bfr[ni] = *(const short8*)(Bs + ((wc * 64 + ni * 16 + r16) * BK + kb * 8));
    #pragma unroll
    for (int mi = 0; mi < 4; mi++)
      #pragma unroll
      for (int ni = 0; ni < 4; ni++)
        acc[mi][ni] = __builtin_amdgcn_mfma_f32_16x16x32_bf16(af[mi], bfr[ni], acc[mi][ni], 0, 0, 0);
    __syncthreads();
  }

  #pragma unroll
  for (int mi = 0; mi < 4; mi++) {
    const int row = bm + wr * 64 + mi * 16 + (lane >> 4) * 4;
    #pragma unroll
    for (int ni = 0; ni < 4; ni++) {
      const int col = bn + wc * 64 + ni * 16 + r16;
      const float bv = (col < N_valid) ? bias[col] : 0.f;
      #pragma unroll
      for (int r = 0; r < 4; r++) {
        const int gr = row + r;
        const float val = acc[mi][ni][r] + bv;
        if constexpr (MODE == 0) {
          if (gr < M_valid && col < N_valid) Cf[(size_t)gr * ldp + col] = val;
        } else if constexpr (MODE == 1) {
          Cb[(size_t)gr * ldp + col] = f2bf(gr < M_valid ? val : 0.f);
        } else {
          if (col < ldp) Cb[(size_t)gr * ldp + col] = f2bf(val);          // xl (bf16 gather table)
          else           Cf[(size_t)gr * ldp + (col - ldp)] = val;        // xr (f32)
        }
      }
    }
  }
}

// ---------------- fused GATv2: flash-style online softmax, one wave per dst ----------------
// Per edge: gather xl row (4 or 2 dims/lane), logit via shfl-reduce, then immediately
// accumulate with online rescale — row never re-read, no LDS, no evals round-trip.

template<int D>
__launch_bounds__(256)
__global__ void gat_fused(const ushort* __restrict__ xlb, const float* __restrict__ xrf,
                          const float* __restrict__ att, const float* __restrict__ bias,
                          const int* __restrict__ offsets, const int* __restrict__ srcs,
                          float* __restrict__ out_f32, ushort* __restrict__ out_bf16,
                          int n_valid, int Etot) {
  constexpr int EPL = D / 64;     // dims per lane
  const int tid  = threadIdx.x;
  const int lane = tid & 63;
  const int wave = tid >> 6;
  const int v    = blockIdx.x * 4 + wave;
  const int d0   = lane * EPL;

  if (v >= n_valid) {             // pad rows -> zero bf16 row
    if (out_bf16) {
      if constexpr (EPL == 4) *(ushort4*)(out_bf16 + (size_t)v * D + d0) = ushort4{0, 0, 0, 0};
      else                    *(ushort2*)(out_bf16 + (size_t)v * D + d0) = ushort2{0, 0};
    }
    return;
  }

  float rv[EPL], av[EPL], acc[EPL];
  #pragma unroll
  for (int d = 0; d < EPL; d++) {
    rv[d]  = xrf[(size_t)v * D + d0 + d];
    av[d]  = att[d0 + d];
    acc[d] = 0.f;
  }

  const int beg = offsets[v], end = offsets[v + 1];
  float m = -INFINITY, s = 0.f;

  ushort xnxt[EPL];
  {
    const int u0 = srcs[beg];
    if constexpr (EPL == 4) *(ushort4*)xnxt = *(const ushort4*)(xlb + (size_t)u0 * D + d0);
    else                    *(ushort2*)xnxt = *(const ushort2*)(xlb + (size_t)u0 * D + d0);
  }

  for (int k = beg; k < end; k++) {
    ushort xcur[EPL];
    #pragma unroll
    for (int d = 0; d < EPL; d++) xcur[d] = xnxt[d];

    // prefetch next edge's row (overlaps the reduce + update below)
    const int kn = (k + 1 < Etot) ? k + 1 : k;
    const int un = srcs[kn];
    if constexpr (EPL == 4) *(ushort4*)xnxt = *(const ushort4*)(xlb + (size_t)un * D + d0);
    else                    *(ushort2*)xnxt = *(const ushort2*)(xlb + (size_t)un * D + d0);

    float xv[EPL], p = 0.f;
    #pragma unroll
    for (int d = 0; d < EPL; d++) {
      xv[d] = bf2f(xcur[d]);
      float t = xv[d] + rv[d];
      t = fmaxf(t, NEG_SLOPE * t);           // leaky_relu (slope 0.2 > 0)
      p = fmaf(t, av[d], p);
    }
    #pragma unroll
    for (int off = 32; off > 0; off >>= 1) p += __shfl_xor(p, off);

    const float m2   = fmaxf(m, p);
    const float cold = __expf(m - m2);       // first edge: exp(-inf) = 0
    const float w    = __expf(p - m2);
    s = s * cold + w;
    #pragma unroll
    for (int d = 0; d < EPL; d++) acc[d] = fmaf(acc[d], cold, w * xv[d]);
    m = m2;
  }

  const float inv = 1.f / s;                 // >=1 edge guaranteed (self-loop)
  float o[EPL];
  #pragma unroll
  for (int d = 0; d < EPL; d++) o[d] = fmaf(acc[d], inv, bias[d0 + d]);

  if (out_f32) {
    if constexpr (EPL == 4) *(float4*)(out_f32 + (size_t)v * D + d0) = float4{o[0], o[1], o[2], o[3]};
    else                    *(float2*)(out_f32 + (size_t)v * D + d0) = float2{o[0], o[1]};
  }
  if (out_bf16) {
    if constexpr (EPL == 4)
      *(ushort4*)(out_bf16 + (size_t)v * D + d0) = ushort4{f2bf(o[0]), f2bf(o[1]), f2bf(o[2]), f2bf(o[3])};
    else
      *(ushort2*)(out_bf16 + (size_t)v * D + d0) = ushort2{f2bf(o[0]), f2bf(o[1])};
  }
}

// ---------------- launch ----------------

extern "C" void kernel_launch(void* const* d_in, const int* in_sizes, int n_in,
                              void* d_out, int out_size, void* d_ws, size_t ws_size,
                              hipStream_t stream) {
  const float* x     = (const float*)d_in[0];
  const int*   eidx  = (const int*)d_in[1];
  const float* Wpi   = (const float*)d_in[2];
  const float* bpi   = (const float*)d_in[3];
  const float* Wl1   = (const float*)d_in[4];
  const float* bl1   = (const float*)d_in[5];
  const float* Wr1   = (const float*)d_in[6];
  const float* br1   = (const float*)d_in[7];
  const float* att1  = (const float*)d_in[8];
  const float* bias1 = (const float*)d_in[9];
  const float* Wl2   = (const float*)d_in[10];
  const float* bl2   = (const float*)d_in[11];
  const float* Wr2   = (const float*)d_in[12];
  const float* br2   = (const float*)d_in[13];
  const float* att2  = (const float*)d_in[14];
  const float* bias2 = (const float*)d_in[15];
  const float* Wpo   = (const float*)d_in[16];
  const float* bpo   = (const float*)d_in[17];

  const int E    = in_sizes[1] / 2;
  const int n    = N_NODES;
  const int Etot = E + n;

  float* out_xhat = (float*)d_out;
  float* out_z    = (float*)d_out + (size_t)N_NODES * D_IN;

  // workspace carve-up
  char* wp = (char*)d_ws;
  auto alloc = [&](size_t bytes) { char* p = wp; wp += (bytes + 255) & ~(size_t)255; return p; };
  char* regionA = (char*)alloc((size_t)MPAD * KPAD_IN * 2);   // xb -> {xr1f,xl1b} -> {xr2f,xl2b}
  ushort* hb_db = (ushort*)alloc((size_t)MPAD * D0 * 2);      // hb then db
  ushort* zb    = (ushort*)alloc((size_t)MPAD * D1 * 2);
  int* counts  = (int*)alloc((size_t)n * 4);
  int* offsets = (int*)alloc((size_t)(n + 1) * 4);
  int* cursors = (int*)alloc((size_t)n * 4);
  int* srcs    = (int*)alloc((size_t)Etot * 4);
  ushort* Wpi_t = (ushort*)alloc((size_t)T_WPI * 2);
  ushort* W1cat = (ushort*)alloc((size_t)T_W1 * 2);
  ushort* W2cat = (ushort*)alloc((size_t)T_W2 * 2);
  ushort* Wpo_t = (ushort*)alloc((size_t)T_WPO * 2);
  float*  bcat1 = (float*)alloc(256 * 4);
  float*  bcat2 = (float*)alloc(512 * 4);

  ushort* xb   = (ushort*)regionA;
  // layer1 intermediates (alias regionA; xb dead by then)
  float*  xr1f = (float*)regionA;                                  // [MPAD][128] f32
  ushort* xl1b = (ushort*)(regionA + 8 * 1024 * 1024);             // [MPAD][128] bf16
  // layer2 intermediates (alias regionA; layer1 dead by then)
  float*  xr2f = (float*)regionA;                                  // [MPAD][256] f32
  ushort* xl2b = (ushort*)(regionA + 12 * 1024 * 1024);            // [MPAD][256] bf16
  ushort* hb   = hb_db;
  ushort* db   = hb_db;

  // CSR
  hipMemsetAsync(counts, 0, (size_t)n * 4, stream);
  const int tb = 256;
  count_kernel<<<(Etot + tb - 1) / tb, tb, 0, stream>>>(eidx, E, n, counts);
  scan_kernel<<<1, 1024, 0, stream>>>(counts, offsets, cursors, n);
  scatter_kernel<<<(Etot + tb - 1) / tb, tb, 0, stream>>>(eidx, E, n, cursors, srcs);

  // prep
  conv_x_kernel<<<MPAD, 256, 0, stream>>>(x, xb);
  wprep_all<<<(T_ALL + 255) / 256, 256, 0, stream>>>(
      Wpi, Wl1, Wr1, Wl2, Wr2, Wpo, bl1, br1, bl2, br2,
      Wpi_t, W1cat, W2cat, Wpo_t, bcat1, bcat2);

  // h = x @ Wpi + bpi  (bf16 out, pad rows zeroed)
  gemm_mfma<1><<<dim3(D0 / 128, MPAD / 128), 256, 0, stream>>>(
      xb, KPAD_IN, Wpi_t, KPAD_IN, bpi, nullptr, hb, D0, N_NODES, D0, KPAD_IN);
  // [xl1(bf16)|xr1(f32)] = h @ [Wl1|Wr1] + [bl1|br1]  (split epilogue, NL=128)
  gemm_mfma<2><<<dim3(256 / 128, MPAD / 128), 256, 0, stream>>>(
      hb, D0, W1cat, D0, bcat1, xr1f, xl1b, D1, N_NODES, 256, D0);
  // GAT1 (fused) -> out_z (f32) + zb (bf16 padded)
  gat_fused<D1><<<MPAD / 4, 256, 0, stream>>>(xl1b, xr1f, att1, bias1,
                                              offsets, srcs, out_z, zb, N_NODES, Etot);
  // [xl2(bf16)|xr2(f32)] = z @ [Wl2|Wr2] + [bl2|br2]  (split epilogue, NL=256)
  gemm_mfma<2><<<dim3(512 / 128, MPAD / 128), 256, 0, stream>>>(
      zb, D1, W2cat, D1, bcat2, xr2f, xl2b, D0, N_NODES, 512, D1);
  // GAT2 (fused) -> db (bf16 padded)
  gat_fused<D0><<<MPAD / 4, 256, 0, stream>>>(xl2b, xr2f, att2, bias2,
                                              offsets, srcs, nullptr, db, N_NODES, Etot);
  // x_hat = d @ Wpo + bpo  (f32 out, guarded)
  gemm_mfma<0><<<dim3(NPAD_OUT / 128, MPAD / 128), 256, 0, stream>>>(
      db, D0, Wpo_t, D0, bpo, out_xhat, nullptr, D_IN, N_NODES, D_IN, D0);
}